// Round 1
// baseline (342.922 us; speedup 1.0000x reference)
//
#include <hip/hip_runtime.h>
#include <math.h>

#define BB 16
#define DD 96
#define TT 512
#define HH 1024
#define NROW (BB*DD)   // 1536
#define RR 8           // rows per block in k_mlp

// ws layout (floats): s[1536] | bn1[96] | bn2[96] | sc[96] | sh[96]
#define WS_S   0
#define WS_BN1 (WS_S + NROW)
#define WS_BN2 (WS_BN1 + DD)
#define WS_SC  (WS_BN2 + DD)
#define WS_SH  (WS_SC + DD)

// K1: s[b,d] = sum_t residual[b,d,t]  (one wave per row)
__global__ __launch_bounds__(64) void k_rowsum(const float* __restrict__ r,
                                               float* __restrict__ s) {
    int row = blockIdx.x;
    int lane = threadIdx.x;
    const float* p = r + (size_t)row * TT;
    float acc = 0.f;
    #pragma unroll
    for (int i = 0; i < TT/64; ++i) acc += p[lane + i*64];
    #pragma unroll
    for (int o = 32; o > 0; o >>= 1) acc += __shfl_down(acc, o, 64);
    if (lane == 0) s[row] = acc;
}

// K2: x[b,i,:] = softmax_j(s_i*s_j/T^1.5) @ r[b,:,:] + r[b,i,:]
//     plus per-channel BN partial sums (atomics into bn1/bn2)
__global__ __launch_bounds__(256) void k_attn(const float* __restrict__ r,
                                              const float* __restrict__ s,
                                              float* __restrict__ x,
                                              float* __restrict__ bn1,
                                              float* __restrict__ bn2) {
    int row = blockIdx.x;          // b*DD + i
    int b = row / DD, i = row % DD;
    int tid = threadIdx.x;
    __shared__ float A[DD];
    __shared__ float wsum[4], wsum2[4];
    const float lscale = 1.0f / (512.0f * 22.627416997969522f);  // T^-1.5
    if (tid < DD) A[tid] = s[b*DD + i] * s[b*DD + tid] * lscale;
    __syncthreads();
    if (tid == 0) {  // serial softmax over 96 — negligible
        float m = -1e30f;
        for (int j = 0; j < DD; ++j) m = fmaxf(m, A[j]);
        float sum = 0.f;
        for (int j = 0; j < DD; ++j) { float e = expf(A[j] - m); A[j] = e; sum += e; }
        float inv = 1.0f / sum;
        for (int j = 0; j < DD; ++j) A[j] *= inv;
    }
    __syncthreads();
    const float* rb = r + (size_t)b * DD * TT;
    float ls = 0.f, ls2 = 0.f;
    for (int t = tid; t < TT; t += 256) {
        float acc = rb[(size_t)i*TT + t];
        for (int j = 0; j < DD; ++j) acc = fmaf(A[j], rb[(size_t)j*TT + t], acc);
        x[(size_t)row*TT + t] = acc;
        ls += acc; ls2 += acc*acc;
    }
    #pragma unroll
    for (int o = 32; o > 0; o >>= 1) {
        ls  += __shfl_down(ls,  o, 64);
        ls2 += __shfl_down(ls2, o, 64);
    }
    int wid = tid >> 6, lane = tid & 63;
    if (lane == 0) { wsum[wid] = ls; wsum2[wid] = ls2; }
    __syncthreads();
    if (tid == 0) {
        atomicAdd(&bn1[i], wsum[0]+wsum[1]+wsum[2]+wsum[3]);
        atomicAdd(&bn2[i], wsum2[0]+wsum2[1]+wsum2[2]+wsum2[3]);
    }
}

// K3: finalize BN -> per-channel affine (scale, shift)
__global__ void k_bn(const float* __restrict__ bn1, const float* __restrict__ bn2,
                     const float* __restrict__ g, const float* __restrict__ bt,
                     float* __restrict__ sc, float* __restrict__ sh) {
    int d = threadIdx.x;
    if (d < DD) {
        const float invn = 1.0f / (float)(BB*TT);
        float mu  = bn1[d] * invn;
        float var = bn2[d] * invn - mu*mu;
        float rs  = rsqrtf(var + 1e-5f);
        float scale = rs * g[d];
        sc[d] = scale;
        sh[d] = bt[d] - mu * scale;
    }
}

// K4: per 8 rows: xn = BN(x); h = gelu(xn@W1+b1); y = h@W2+b2+xn; out = LN(y)
__global__ __launch_bounds__(512) void k_mlp(const float* __restrict__ x,
                                             const float* __restrict__ sc,
                                             const float* __restrict__ sh,
                                             const float* __restrict__ W1,
                                             const float* __restrict__ b1,
                                             const float* __restrict__ W2,
                                             const float* __restrict__ b2,
                                             const float* __restrict__ lng,
                                             const float* __restrict__ lnb,
                                             float* __restrict__ out) {
    __shared__ __align__(16) float xs[RR][TT];   // 16 KB
    __shared__ __align__(16) float hs[RR][HH];   // 32 KB
    __shared__ float red[8][2];
    int tid = threadIdx.x;       // 512 threads = 8 waves
    int row0 = blockIdx.x * RR;

    // load + BN affine (one element/thread/row)
    #pragma unroll
    for (int rr = 0; rr < RR; ++rr) {
        int row = row0 + rr;
        int d = row % DD;
        xs[rr][tid] = x[(size_t)row*TT + tid] * sc[d] + sh[d];
    }
    __syncthreads();

    // h = gelu(xn @ W1 + b1): thread owns cols {tid, 512+tid} for all 8 rows
    float acc[2][RR];
    #pragma unroll
    for (int jb = 0; jb < 2; ++jb) {
        float bj = b1[jb*512 + tid];
        #pragma unroll
        for (int rr = 0; rr < RR; ++rr) acc[jb][rr] = bj;
    }
    for (int t4 = 0; t4 < TT/4; ++t4) {
        float xv[RR][4];
        #pragma unroll
        for (int rr = 0; rr < RR; ++rr) {
            float4 v = reinterpret_cast<const float4*>(&xs[rr][0])[t4];
            xv[rr][0]=v.x; xv[rr][1]=v.y; xv[rr][2]=v.z; xv[rr][3]=v.w;
        }
        #pragma unroll
        for (int u = 0; u < 4; ++u) {
            int t = 4*t4 + u;
            const float* wr = &W1[(size_t)t*HH + tid];
            #pragma unroll
            for (int jb = 0; jb < 2; ++jb) {
                float w = wr[jb*512];
                #pragma unroll
                for (int rr = 0; rr < RR; ++rr)
                    acc[jb][rr] = fmaf(xv[rr][u], w, acc[jb][rr]);
            }
        }
    }
    #pragma unroll
    for (int jb = 0; jb < 2; ++jb) {
        int j = jb*512 + tid;
        #pragma unroll
        for (int rr = 0; rr < RR; ++rr) {
            float v = acc[jb][rr];
            hs[rr][j] = 0.5f * v * (1.0f + erff(v * 0.7071067811865475f));
        }
    }
    __syncthreads();

    // y = h @ W2 + b2 + xn: thread owns output col tid for all 8 rows
    float ya[RR];
    {
        float bt = b2[tid];
        #pragma unroll
        for (int rr = 0; rr < RR; ++rr) ya[rr] = bt;
    }
    for (int j4 = 0; j4 < HH/4; ++j4) {
        float hv[RR][4];
        #pragma unroll
        for (int rr = 0; rr < RR; ++rr) {
            float4 v = reinterpret_cast<const float4*>(&hs[rr][0])[j4];
            hv[rr][0]=v.x; hv[rr][1]=v.y; hv[rr][2]=v.z; hv[rr][3]=v.w;
        }
        #pragma unroll
        for (int u = 0; u < 4; ++u) {
            int j = 4*j4 + u;
            float w = W2[(size_t)j*TT + tid];
            #pragma unroll
            for (int rr = 0; rr < RR; ++rr)
                ya[rr] = fmaf(hv[rr][u], w, ya[rr]);
        }
    }
    #pragma unroll
    for (int rr = 0; rr < RR; ++rr) ya[rr] += xs[rr][tid];

    // LayerNorm per row over T=512 (one value/thread)
    int wid = tid >> 6, lane = tid & 63;
    float lg = lng[tid], lb = lnb[tid];
    for (int rr = 0; rr < RR; ++rr) {
        float v = ya[rr];
        float ls = v, ls2 = v*v;
        #pragma unroll
        for (int o = 32; o > 0; o >>= 1) {
            ls  += __shfl_down(ls,  o, 64);
            ls2 += __shfl_down(ls2, o, 64);
        }
        if (lane == 0) { red[wid][0] = ls; red[wid][1] = ls2; }
        __syncthreads();
        float sum = 0.f, sum2 = 0.f;
        #pragma unroll
        for (int w8 = 0; w8 < 8; ++w8) { sum += red[w8][0]; sum2 += red[w8][1]; }
        float mu  = sum  * (1.0f/TT);
        float var = sum2 * (1.0f/TT) - mu*mu;
        float rs  = rsqrtf(var + 1e-5f);
        out[(size_t)(row0+rr)*TT + tid] = (v - mu) * rs * lg + lb;
        __syncthreads();
    }
}

extern "C" void kernel_launch(void* const* d_in, const int* in_sizes, int n_in,
                              void* d_out, int out_size, void* d_ws, size_t ws_size,
                              hipStream_t stream) {
    (void)in_sizes; (void)n_in; (void)out_size; (void)ws_size;
    const float* residual = (const float*)d_in[0];
    const float* bng = (const float*)d_in[1];
    const float* bnb = (const float*)d_in[2];
    const float* lng = (const float*)d_in[3];
    const float* lnb = (const float*)d_in[4];
    const float* W1  = (const float*)d_in[5];
    const float* b1  = (const float*)d_in[6];
    const float* W2  = (const float*)d_in[7];
    const float* b2  = (const float*)d_in[8];
    float* out = (float*)d_out;
    float* ws  = (float*)d_ws;
    float* s   = ws + WS_S;
    float* bn1 = ws + WS_BN1;
    float* bn2 = ws + WS_BN2;
    float* sc  = ws + WS_SC;
    float* sh  = ws + WS_SH;
    // use d_out as scratch for the intermediate x (exactly NROW*TT floats);
    // k_mlp reads only its own rows before overwriting them.
    float* xbuf = out;

    hipMemsetAsync(bn1, 0, 2*DD*sizeof(float), stream);   // zero bn1+bn2
    k_rowsum<<<NROW, 64, 0, stream>>>(residual, s);
    k_attn<<<NROW, 256, 0, stream>>>(residual, s, xbuf, bn1, bn2);
    k_bn<<<1, 128, 0, stream>>>(bn1, bn2, bng, bnb, sc, sh);
    k_mlp<<<NROW/RR, 512, 0, stream>>>(xbuf, sc, sh, W1, b1, W2, b2, lng, lnb, out);
}

// Round 3
// 174.858 us; speedup vs baseline: 1.9611x; 1.9611x over previous
//
#include <hip/hip_runtime.h>
#include <math.h>
#include <stdint.h>

#define BB 16
#define DD 96
#define TT 512
#define HH 1024
#define NROW (BB*DD)   // 1536

typedef __attribute__((ext_vector_type(4))) float floatx4;
typedef __attribute__((ext_vector_type(8))) short short8;

// ---------------- ws layout (bytes) ----------------
// region1: x fp32 [1536*512] (3 MB), later reused as h_bf16 [1536*1024] (3 MB)
#define WSOFF_X     0
#define WSOFF_H     0
#define WSOFF_XNBF  (3*1024*1024)            // 1536*512 ushort = 1.5 MB
#define WSOFF_W1BF  (WSOFF_XNBF + 1536*512*2)      // 1 MB
#define WSOFF_W2BF  (WSOFF_W1BF + 512*1024*2)      // 1 MB
#define WSOFF_A     (WSOFF_W2BF + 1024*512*2)      // 16*96*96 fp32 = 576 KB
#define WSOFF_S     (WSOFF_A + 16*96*96*4)         // 1536 fp32
#define WSOFF_BN1   (WSOFF_S + 1536*4)
#define WSOFF_BN2   (WSOFF_BN1 + 96*4)
#define WSOFF_SC    (WSOFF_BN2 + 96*4)
#define WSOFF_SH    (WSOFF_SC + 96*4)

// bf16 round-to-nearest-even, no header dependence
__device__ __forceinline__ uint16_t f2bf(float v) {
    uint32_t u = __float_as_uint(v);
    uint32_t r = 0x7fffu + ((u >> 16) & 1u);
    return (uint16_t)((u + r) >> 16);
}
__device__ __forceinline__ float bf2f(uint16_t v) {
    return __uint_as_float(((uint32_t)v) << 16);
}

// K1: s[row] = sum_t residual[row,t]
__global__ __launch_bounds__(64) void k_rowsum(const float* __restrict__ r,
                                               float* __restrict__ s) {
    int row = blockIdx.x;
    int lane = threadIdx.x;
    const float* p = r + (size_t)row * TT;
    float acc = 0.f;
    #pragma unroll
    for (int i = 0; i < TT/64; ++i) acc += p[lane + i*64];
    #pragma unroll
    for (int o = 32; o > 0; o >>= 1) acc += __shfl_down(acc, o, 64);
    if (lane == 0) s[row] = acc;
}

// K2: A[b][i][j] = softmax_j(s_i*s_j/T^1.5)   (thread i of block b)
__global__ __launch_bounds__(128) void k_softA(const float* __restrict__ s,
                                               float* __restrict__ A) {
    int b = blockIdx.x;
    int i = threadIdx.x;
    __shared__ float sl[DD];
    if (i < DD) sl[i] = s[b*DD + i];
    __syncthreads();
    if (i >= DD) return;
    const float c = 1.0f / (512.0f * 22.627416997969522f);  // T^-1.5
    float si = sl[i] * c;
    float m = -1e30f;
    for (int j = 0; j < DD; ++j) m = fmaxf(m, si * sl[j]);
    float sum = 0.f;
    for (int j = 0; j < DD; ++j) sum += expf(si * sl[j] - m);
    float inv = 1.0f / sum;
    float* Ao = A + ((size_t)b*DD + i)*DD;
    for (int j = 0; j < DD; ++j) Ao[j] = expf(si * sl[j] - m) * inv;
}

// K3: x[b,:,chunk] = A[b] @ r[b,:,chunk] + r[b,:,chunk]; BN partial sums
// grid (16 b, 8 chunks) x 256
__global__ __launch_bounds__(256) void k_attn2(const float* __restrict__ r,
                                               const float* __restrict__ A,
                                               float* __restrict__ x,
                                               float* __restrict__ bn1,
                                               float* __restrict__ bn2) {
    __shared__ float rlds[DD*64];     // [j][t]  24 KB
    __shared__ float Alds[DD*DD];     // [i][j]  36 KB
    int b = blockIdx.x, chunk = blockIdx.y;
    int tid = threadIdx.x;
    int t0 = chunk * 64;
    const float* rb = r + (size_t)b*DD*TT;
    // stage r-chunk: 6144 floats
    for (int s = 0; s < DD*64/256; ++s) {
        int idx = tid + s*256;
        int i = idx >> 6, t = idx & 63;
        rlds[idx] = rb[(size_t)i*TT + t0 + t];
    }
    // stage A[b]: 9216 floats
    const float* Ab = A + (size_t)b*DD*DD;
    for (int s = 0; s < DD*DD/256; ++s) Alds[tid + s*256] = Ab[tid + s*256];
    __syncthreads();

    int wave = tid >> 6, lane = tid & 63;
    int t = lane;
    for (int ib = 0; ib < 6; ++ib) {
        int i = wave*24 + ib*4;
        float acc[4];
        #pragma unroll
        for (int u = 0; u < 4; ++u) acc[u] = rlds[(i+u)*64 + t];  // residual
        for (int j = 0; j < DD; j += 4) {
            float4 aa[4];
            #pragma unroll
            for (int u = 0; u < 4; ++u)
                aa[u] = *reinterpret_cast<const float4*>(&Alds[(i+u)*DD + j]);
            #pragma unroll
            for (int jj = 0; jj < 4; ++jj) {
                float rv = rlds[(j+jj)*64 + t];
                acc[0] = fmaf(((const float*)&aa[0])[jj], rv, acc[0]);
                acc[1] = fmaf(((const float*)&aa[1])[jj], rv, acc[1]);
                acc[2] = fmaf(((const float*)&aa[2])[jj], rv, acc[2]);
                acc[3] = fmaf(((const float*)&aa[3])[jj], rv, acc[3]);
            }
        }
        #pragma unroll
        for (int u = 0; u < 4; ++u) {
            x[((size_t)b*DD + i + u)*TT + t0 + t] = acc[u];
            float ls = acc[u], ls2 = acc[u]*acc[u];
            #pragma unroll
            for (int o = 32; o > 0; o >>= 1) {
                ls  += __shfl_down(ls,  o, 64);
                ls2 += __shfl_down(ls2, o, 64);
            }
            if (lane == 0) {
                atomicAdd(&bn1[i+u], ls);
                atomicAdd(&bn2[i+u], ls2);
            }
        }
    }
}

// K4: finalize BN
__global__ void k_bn(const float* __restrict__ bn1, const float* __restrict__ bn2,
                     const float* __restrict__ g, const float* __restrict__ bt,
                     float* __restrict__ sc, float* __restrict__ sh) {
    int d = threadIdx.x;
    if (d < DD) {
        const float invn = 1.0f / (float)(BB*TT);
        float mu  = bn1[d] * invn;
        float var = bn2[d] * invn - mu*mu;
        float rs  = rsqrtf(var + 1e-5f);
        float scale = rs * g[d];
        sc[d] = scale;
        sh[d] = bt[d] - mu * scale;
    }
}

// K5: xn_bf = bf16(BN(x)); grid 768 x 256, 4 elems/thread
__global__ __launch_bounds__(256) void k_bnx(const float* __restrict__ x,
                                             const float* __restrict__ sc,
                                             const float* __restrict__ sh,
                                             uint16_t* __restrict__ xnbf) {
    int base = (blockIdx.x*256 + threadIdx.x) * 4;
    int row = base >> 9;
    int d = row % DD;
    float4 v = *reinterpret_cast<const float4*>(&x[base]);
    float scd = sc[d], shd = sh[d];
    ushort4 o;
    o.x = f2bf(v.x*scd + shd);
    o.y = f2bf(v.y*scd + shd);
    o.z = f2bf(v.z*scd + shd);
    o.w = f2bf(v.w*scd + shd);
    *reinterpret_cast<ushort4*>(&xnbf[base]) = o;
}

// K6: swizzle W1/W2 fp32 -> bf16 B-fragment layout.
// Layout: flat[((tile_n*KT + tile_k)*64 + lane)*8 + j]
//       = W[(tile_k*32 + (lane>>4)*8 + j)*N + tile_n*16 + (lane&15)]
// grid 2048 x 64: blocks [0,1024) -> W1 (K=512,N=1024,KT=16); [1024,2048) -> W2 (K=1024,N=512,KT=32)
__global__ __launch_bounds__(64) void k_wswiz(const float* __restrict__ W1,
                                              const float* __restrict__ W2,
                                              uint16_t* __restrict__ w1bf,
                                              uint16_t* __restrict__ w2bf) {
    int blk = blockIdx.x;
    int lane = threadIdx.x;
    int q = lane >> 4, l15 = lane & 15;
    const float* W; uint16_t* out; int KT, N, b;
    if (blk < 1024) { W = W1; out = w1bf; KT = 16; N = 1024; b = blk; }
    else            { W = W2; out = w2bf; KT = 32; N = 512;  b = blk - 1024; }
    int tile_n = b / KT, tile_k = b % KT;
    const float* src = W + (size_t)(tile_k*32 + q*8)*N + tile_n*16 + l15;
    uint16_t tmp[8];
    #pragma unroll
    for (int j = 0; j < 8; ++j) tmp[j] = f2bf(src[(size_t)j*N]);
    uint16_t* dst = out + ((size_t)b*64 + lane)*8;
    *reinterpret_cast<ushort4*>(dst)     = *reinterpret_cast<ushort4*>(&tmp[0]);
    *reinterpret_cast<ushort4*>(dst + 4) = *reinterpret_cast<ushort4*>(&tmp[4]);
}

// K7: h = gelu(xn @ W1 + b1) -> bf16.  grid (48, 8) x 256. Tile M=32, N=128 (wave: 32x32).
__global__ __launch_bounds__(256) void k_gemm1(const uint16_t* __restrict__ xnbf,
                                               const uint16_t* __restrict__ w1bf,
                                               const float* __restrict__ b1,
                                               uint16_t* __restrict__ hbf) {
    int tid = threadIdx.x;
    int wave = tid >> 6, lane = tid & 63;
    int q = lane >> 4, l15 = lane & 15;
    int m0 = blockIdx.x * 32;
    int n0 = blockIdx.y * 128 + wave * 32;
    floatx4 acc[2][2] = {};
    const uint16_t* a0p = xnbf + (size_t)(m0 + l15)*TT + q*8;
    const uint16_t* a1p = a0p + 16*TT;
    const uint16_t* b0p = w1bf + ((size_t)((n0>>4)    )*16*64 + lane)*8;
    const uint16_t* b1p = w1bf + ((size_t)((n0>>4) + 1)*16*64 + lane)*8;
    for (int kk = 0; kk < 16; ++kk) {
        short8 a0 = *reinterpret_cast<const short8*>(a0p + kk*32);
        short8 a1 = *reinterpret_cast<const short8*>(a1p + kk*32);
        short8 b0 = *reinterpret_cast<const short8*>(b0p + kk*512);
        short8 b1 = *reinterpret_cast<const short8*>(b1p + kk*512);
        acc[0][0] = __builtin_amdgcn_mfma_f32_16x16x32_bf16(a0, b0, acc[0][0], 0, 0, 0);
        acc[0][1] = __builtin_amdgcn_mfma_f32_16x16x32_bf16(a0, b1, acc[0][1], 0, 0, 0);
        acc[1][0] = __builtin_amdgcn_mfma_f32_16x16x32_bf16(a1, b0, acc[1][0], 0, 0, 0);
        acc[1][1] = __builtin_amdgcn_mfma_f32_16x16x32_bf16(a1, b1, acc[1][1], 0, 0, 0);
    }
    #pragma unroll
    for (int nf = 0; nf < 2; ++nf) {
        int col = n0 + nf*16 + l15;
        float bias = b1[col];
        #pragma unroll
        for (int mf = 0; mf < 2; ++mf) {
            #pragma unroll
            for (int r = 0; r < 4; ++r) {
                int row = m0 + mf*16 + q*4 + r;
                float v = acc[mf][nf][r] + bias;
                float g = 0.5f * v * (1.0f + erff(v * 0.7071067811865475f));
                hbf[(size_t)row*HH + col] = f2bf(g);
            }
        }
    }
}

// K8: y = h @ W2 + b2 + xn -> fp32 (d_out). grid (48, 4) x 256. Tile M=32, N=128.
__global__ __launch_bounds__(256) void k_gemm2(const uint16_t* __restrict__ hbf,
                                               const uint16_t* __restrict__ w2bf,
                                               const float* __restrict__ b2,
                                               const uint16_t* __restrict__ xnbf,
                                               float* __restrict__ y) {
    int tid = threadIdx.x;
    int wave = tid >> 6, lane = tid & 63;
    int q = lane >> 4, l15 = lane & 15;
    int m0 = blockIdx.x * 32;
    int n0 = blockIdx.y * 128 + wave * 32;
    floatx4 acc[2][2] = {};
    const uint16_t* a0p = hbf + (size_t)(m0 + l15)*HH + q*8;
    const uint16_t* a1p = a0p + 16*HH;
    const uint16_t* b0p = w2bf + ((size_t)((n0>>4)    )*32*64 + lane)*8;
    const uint16_t* b1p = w2bf + ((size_t)((n0>>4) + 1)*32*64 + lane)*8;
    for (int kk = 0; kk < 32; ++kk) {
        short8 a0 = *reinterpret_cast<const short8*>(a0p + kk*32);
        short8 a1 = *reinterpret_cast<const short8*>(a1p + kk*32);
        short8 b0 = *reinterpret_cast<const short8*>(b0p + kk*512);
        short8 b1 = *reinterpret_cast<const short8*>(b1p + kk*512);
        acc[0][0] = __builtin_amdgcn_mfma_f32_16x16x32_bf16(a0, b0, acc[0][0], 0, 0, 0);
        acc[0][1] = __builtin_amdgcn_mfma_f32_16x16x32_bf16(a0, b1, acc[0][1], 0, 0, 0);
        acc[1][0] = __builtin_amdgcn_mfma_f32_16x16x32_bf16(a1, b0, acc[1][0], 0, 0, 0);
        acc[1][1] = __builtin_amdgcn_mfma_f32_16x16x32_bf16(a1, b1, acc[1][1], 0, 0, 0);
    }
    #pragma unroll
    for (int nf = 0; nf < 2; ++nf) {
        int col = n0 + nf*16 + l15;
        float bias = b2[col];
        #pragma unroll
        for (int mf = 0; mf < 2; ++mf) {
            #pragma unroll
            for (int r = 0; r < 4; ++r) {
                int row = m0 + mf*16 + q*4 + r;
                float xb = bf2f(xnbf[(size_t)row*TT + col]);
                y[(size_t)row*TT + col] = acc[mf][nf][r] + bias + xb;
            }
        }
    }
}

// K9: LayerNorm per row over T=512, in-place on d_out. grid 1536 x 64.
__global__ __launch_bounds__(64) void k_ln(float* __restrict__ y,
                                           const float* __restrict__ lng,
                                           const float* __restrict__ lnb) {
    int row = blockIdx.x;
    int lane = threadIdx.x;
    float4* p = reinterpret_cast<float4*>(y + (size_t)row*TT);
    float4 v0 = p[lane*2], v1 = p[lane*2 + 1];
    float s  = v0.x+v0.y+v0.z+v0.w + v1.x+v1.y+v1.z+v1.w;
    float s2 = v0.x*v0.x+v0.y*v0.y+v0.z*v0.z+v0.w*v0.w
             + v1.x*v1.x+v1.y*v1.y+v1.z*v1.z+v1.w*v1.w;
    #pragma unroll
    for (int o = 1; o < 64; o <<= 1) {
        s  += __shfl_xor(s,  o, 64);
        s2 += __shfl_xor(s2, o, 64);
    }
    float mu = s * (1.0f/TT);
    float var = s2 * (1.0f/TT) - mu*mu;
    float rs = rsqrtf(var + 1e-5f);
    const float4* g4 = reinterpret_cast<const float4*>(lng);
    const float4* b4 = reinterpret_cast<const float4*>(lnb);
    float4 g0 = g4[lane*2], g1 = g4[lane*2+1];
    float4 bb0 = b4[lane*2], bb1 = b4[lane*2+1];
    float4 o0, o1;
    o0.x = (v0.x-mu)*rs*g0.x + bb0.x;  o0.y = (v0.y-mu)*rs*g0.y + bb0.y;
    o0.z = (v0.z-mu)*rs*g0.z + bb0.z;  o0.w = (v0.w-mu)*rs*g0.w + bb0.w;
    o1.x = (v1.x-mu)*rs*g1.x + bb1.x;  o1.y = (v1.y-mu)*rs*g1.y + bb1.y;
    o1.z = (v1.z-mu)*rs*g1.z + bb1.z;  o1.w = (v1.w-mu)*rs*g1.w + bb1.w;
    p[lane*2] = o0;  p[lane*2+1] = o1;
}

extern "C" void kernel_launch(void* const* d_in, const int* in_sizes, int n_in,
                              void* d_out, int out_size, void* d_ws, size_t ws_size,
                              hipStream_t stream) {
    (void)in_sizes; (void)n_in; (void)out_size; (void)ws_size;
    const float* residual = (const float*)d_in[0];
    const float* bng = (const float*)d_in[1];
    const float* bnb = (const float*)d_in[2];
    const float* lng = (const float*)d_in[3];
    const float* lnb = (const float*)d_in[4];
    const float* W1  = (const float*)d_in[5];
    const float* b1  = (const float*)d_in[6];
    const float* W2  = (const float*)d_in[7];
    const float* b2  = (const float*)d_in[8];
    float* out = (float*)d_out;
    char* ws = (char*)d_ws;
    float*    x    = (float*)(ws + WSOFF_X);
    uint16_t* hbf  = (uint16_t*)(ws + WSOFF_H);     // aliases x; x dead by then
    uint16_t* xnbf = (uint16_t*)(ws + WSOFF_XNBF);
    uint16_t* w1bf = (uint16_t*)(ws + WSOFF_W1BF);
    uint16_t* w2bf = (uint16_t*)(ws + WSOFF_W2BF);
    float*    A    = (float*)(ws + WSOFF_A);
    float*    s    = (float*)(ws + WSOFF_S);
    float*    bn1  = (float*)(ws + WSOFF_BN1);
    float*    bn2  = (float*)(ws + WSOFF_BN2);
    float*    sc   = (float*)(ws + WSOFF_SC);
    float*    sh   = (float*)(ws + WSOFF_SH);

    (void)hipMemsetAsync(bn1, 0, 2*DD*sizeof(float), stream);
    k_rowsum<<<NROW, 64, 0, stream>>>(residual, s);
    k_softA<<<BB, 128, 0, stream>>>(s, A);
    k_wswiz<<<2048, 64, 0, stream>>>(W1, W2, w1bf, w2bf);
    k_attn2<<<dim3(BB, 8), 256, 0, stream>>>(residual, A, x, bn1, bn2);
    k_bn<<<1, 128, 0, stream>>>(bn1, bn2, bng, bnb, sc, sh);
    k_bnx<<<NROW*TT/1024, 256, 0, stream>>>(x, sc, sh, xnbf);
    k_gemm1<<<dim3(48, 8), 256, 0, stream>>>(xnbf, w1bf, b1, hbf);
    k_gemm2<<<dim3(48, 4), 256, 0, stream>>>(hbf, w2bf, b2, xnbf, out);
    k_ln<<<NROW, 64, 0, stream>>>(out, lng, lnb);
}

// Round 5
// 170.767 us; speedup vs baseline: 2.0081x; 1.0240x over previous
//
#include <hip/hip_runtime.h>
#include <math.h>
#include <stdint.h>

#define BB 16
#define DD 96
#define TT 512
#define HH 1024
#define NROW (BB*DD)   // 1536

typedef __attribute__((ext_vector_type(4))) float floatx4;
typedef __attribute__((ext_vector_type(8))) short short8;

// ---------------- ws layout (bytes) ----------------
// region1: x fp32 [1536*512] (3MB), later reused as h bf16 frag-order [1536*1024] (3MB)
#define WSOFF_X     0
#define WSOFF_HFRAG 0
#define WSOFF_XROW  (3*1024*1024)                   // xn row-major bf16, 1.5MB
#define WSOFF_XFRAG (WSOFF_XROW + NROW*TT*2)        // xn gemm1-A-frag bf16, 1.5MB
#define WSOFF_W1BF  (WSOFF_XFRAG + NROW*TT*2)       // 1MB
#define WSOFF_W2BF  (WSOFF_W1BF + TT*HH*2)          // 1MB
#define WSOFF_A     (WSOFF_W2BF + HH*TT*2)          // 16*96*96 fp32 = 576KB
#define WSOFF_S     (WSOFF_A + BB*DD*DD*4)
#define WSOFF_BN1   (WSOFF_S + NROW*4)
#define WSOFF_BN2   (WSOFF_BN1 + DD*4)
#define WSOFF_SC    (WSOFF_BN2 + DD*4)
#define WSOFF_SH    (WSOFF_SC + DD*4)

// bf16 round-to-nearest-even, no header dependence
__device__ __forceinline__ uint16_t f2bf(float v) {
    uint32_t u = __float_as_uint(v);
    uint32_t r = 0x7fffu + ((u >> 16) & 1u);
    return (uint16_t)((u + r) >> 16);
}
__device__ __forceinline__ float bf2f(uint16_t v) {
    return __uint_as_float(((uint32_t)v) << 16);
}

// gemm1 A-frag slot: xn[row][k], K=512 -> 16 k-tiles of 32.  (R4 bug: used 32 -> 3MB overflow into w1bf)
#define KT1 (TT/32)    // 16
__device__ __forceinline__ size_t afrag1_slot(int row, int k) {
    return ((size_t)((row >> 4)*KT1 + (k >> 5))*64 + ((k >> 3) & 3)*16 + (row & 15));
}
// gemm2 A-frag: h[row][k], K=1024 -> 32 k-tiles
#define KT2 (HH/32)    // 32

// K1: s[row] = sum_t residual[row,t]
__global__ __launch_bounds__(64) void k_rowsum(const float* __restrict__ r,
                                               float* __restrict__ s) {
    int row = blockIdx.x;
    int lane = threadIdx.x;
    const float* p = r + (size_t)row * TT;
    float acc = 0.f;
    #pragma unroll
    for (int i = 0; i < TT/64; ++i) acc += p[lane + i*64];
    #pragma unroll
    for (int o = 32; o > 0; o >>= 1) acc += __shfl_down(acc, o, 64);
    if (lane == 0) s[row] = acc;
}

// K2: A[b][i][j] = softmax_j(s_i*s_j/T^1.5)
__global__ __launch_bounds__(128) void k_softA(const float* __restrict__ s,
                                               float* __restrict__ A) {
    int b = blockIdx.x;
    int i = threadIdx.x;
    __shared__ float sl[DD];
    if (i < DD) sl[i] = s[b*DD + i];
    __syncthreads();
    if (i >= DD) return;
    const float c = 1.0f / (512.0f * 22.627416997969522f);  // T^-1.5
    float si = sl[i] * c;
    float m = -1e30f;
    for (int j = 0; j < DD; ++j) m = fmaxf(m, si * sl[j]);
    float sum = 0.f;
    for (int j = 0; j < DD; ++j) sum += expf(si * sl[j] - m);
    float inv = 1.0f / sum;
    float* Ao = A + ((size_t)b*DD + i)*DD;
    for (int j = 0; j < DD; ++j) Ao[j] = expf(si * sl[j] - m) * inv;
}

// K3: x[b,rows,chunk] = A[b,rows] @ r[b,:,chunk] + r[b,rows,chunk]; BN partials.
// grid (16 b, 8 tchunk, 4 rowgroup) x 256. A read via wave-uniform s_loads.
__global__ __launch_bounds__(256) void k_attn3(const float* __restrict__ r,
                                               const float* __restrict__ A,
                                               float* __restrict__ x,
                                               float* __restrict__ bn1,
                                               float* __restrict__ bn2) {
    __shared__ float rlds[DD*64];     // [i][t] 24 KB, all 96 rows of this chunk
    int b = blockIdx.x, chunk = blockIdx.y, ig = blockIdx.z;
    int tid = threadIdx.x;
    int t0 = chunk * 64;
    const float4* rb4 = reinterpret_cast<const float4*>(r + (size_t)b*DD*TT);
    float4* rl4 = reinterpret_cast<float4*>(rlds);
    // stage all 96 rows x 64 t: 1536 float4
    #pragma unroll
    for (int s = 0; s < 6; ++s) {
        int idx = tid + s*256;
        int i = idx >> 4, t4 = idx & 15;
        rl4[idx] = rb4[(size_t)i*(TT/4) + (t0 >> 2) + t4];
    }
    __syncthreads();

    int wave = __builtin_amdgcn_readfirstlane(tid >> 6);
    int lane = tid & 63;
    int i0 = ig*24 + wave*6;          // this wave's first row
    const float* Ab = A + ((size_t)b*DD + i0)*DD;   // wave-uniform

    float acc[6];
    #pragma unroll
    for (int rr = 0; rr < 6; ++rr) acc[rr] = rlds[(i0+rr)*64 + lane];  // residual
    #pragma unroll 4
    for (int j4 = 0; j4 < DD/4; ++j4) {
        float4 a[6];
        #pragma unroll
        for (int rr = 0; rr < 6; ++rr)
            a[rr] = *reinterpret_cast<const float4*>(Ab + rr*DD + j4*4);  // s_load
        float rv[4];
        #pragma unroll
        for (int u = 0; u < 4; ++u) rv[u] = rlds[(j4*4+u)*64 + lane];
        #pragma unroll
        for (int rr = 0; rr < 6; ++rr) {
            acc[rr] = fmaf(a[rr].x, rv[0], acc[rr]);
            acc[rr] = fmaf(a[rr].y, rv[1], acc[rr]);
            acc[rr] = fmaf(a[rr].z, rv[2], acc[rr]);
            acc[rr] = fmaf(a[rr].w, rv[3], acc[rr]);
        }
    }
    #pragma unroll
    for (int rr = 0; rr < 6; ++rr) {
        int i = i0 + rr;
        x[((size_t)b*DD + i)*TT + t0 + lane] = acc[rr];
        float ls = acc[rr], ls2 = acc[rr]*acc[rr];
        #pragma unroll
        for (int o = 32; o > 0; o >>= 1) {
            ls  += __shfl_down(ls,  o, 64);
            ls2 += __shfl_down(ls2, o, 64);
        }
        if (lane == 0) {
            atomicAdd(&bn1[i], ls);
            atomicAdd(&bn2[i], ls2);
        }
    }
}

// K4: finalize BN
__global__ void k_bn(const float* __restrict__ bn1, const float* __restrict__ bn2,
                     const float* __restrict__ g, const float* __restrict__ bt,
                     float* __restrict__ sc, float* __restrict__ sh) {
    int d = threadIdx.x;
    if (d < DD) {
        const float invn = 1.0f / (float)(BB*TT);
        float mu  = bn1[d] * invn;
        float var = bn2[d] * invn - mu*mu;
        float rs  = rsqrtf(var + 1e-5f);
        float scale = rs * g[d];
        sc[d] = scale;
        sh[d] = bt[d] - mu * scale;
    }
}

// K5: xn = BN(x) -> bf16, written BOTH row-major and gemm1-A-frag order.
// grid 768 x 256; thread: 4 consecutive k of one row.
__global__ __launch_bounds__(256) void k_bnx(const float* __restrict__ x,
                                             const float* __restrict__ sc,
                                             const float* __restrict__ sh,
                                             uint16_t* __restrict__ xrow,
                                             uint16_t* __restrict__ xfrag) {
    int g = blockIdx.x*256 + threadIdx.x;
    int row = g >> 7;
    int k0 = (g & 127) * 4;
    int d = row % DD;
    float4 v = *reinterpret_cast<const float4*>(&x[(size_t)row*TT + k0]);
    float scd = sc[d], shd = sh[d];
    ushort4 o;
    o.x = f2bf(v.x*scd + shd);
    o.y = f2bf(v.y*scd + shd);
    o.z = f2bf(v.z*scd + shd);
    o.w = f2bf(v.w*scd + shd);
    *reinterpret_cast<ushort4*>(&xrow[(size_t)row*TT + k0]) = o;
    // frag order: slot covers k..k+7; k0%8 in {0,4} -> 8B-aligned half-slot
    size_t slot = afrag1_slot(row, k0);
    *reinterpret_cast<ushort4*>(&xfrag[slot*8 + (k0 & 7)]) = o;
}

// K6: swizzle W1/W2 fp32 -> bf16 B-fragment layout.
__global__ __launch_bounds__(64) void k_wswiz(const float* __restrict__ W1,
                                              const float* __restrict__ W2,
                                              uint16_t* __restrict__ w1bf,
                                              uint16_t* __restrict__ w2bf) {
    int blk = blockIdx.x;
    int lane = threadIdx.x;
    int q = lane >> 4, l15 = lane & 15;
    const float* W; uint16_t* out; int KT, N, b;
    if (blk < 1024) { W = W1; out = w1bf; KT = 16; N = 1024; b = blk; }
    else            { W = W2; out = w2bf; KT = 32; N = 512;  b = blk - 1024; }
    int tile_n = b / KT, tile_k = b % KT;
    const float* src = W + (size_t)(tile_k*32 + q*8)*N + tile_n*16 + l15;
    uint16_t tmp[8];
    #pragma unroll
    for (int j = 0; j < 8; ++j) tmp[j] = f2bf(src[(size_t)j*N]);
    uint16_t* dst = out + ((size_t)b*64 + lane)*8;
    *reinterpret_cast<ushort4*>(dst)     = *reinterpret_cast<ushort4*>(&tmp[0]);
    *reinterpret_cast<ushort4*>(dst + 4) = *reinterpret_cast<ushort4*>(&tmp[4]);
}

// K7: h = gelu(xn @ W1 + b1), output in gemm2-A-frag order.
// grid (48, 8) x 256. Tile M=32, N=128. All K-loop loads coalesced streams.
__global__ __launch_bounds__(256) void k_gemm1(const uint16_t* __restrict__ xfrag,
                                               const uint16_t* __restrict__ w1bf,
                                               const float* __restrict__ b1,
                                               uint16_t* __restrict__ hfrag) {
    __shared__ __align__(16) uint16_t cs[32][136];   // C-tile transpose buffer, 8.5 KB
    int tid = threadIdx.x;
    int wave = tid >> 6, lane = tid & 63;
    int q = lane >> 4, l15 = lane & 15;
    int mtile0 = blockIdx.x * 2;       // two 16-row A tiles
    int n0 = blockIdx.y * 128 + wave * 32;
    floatx4 acc[2][2] = {};
    const uint16_t* a0p = xfrag + ((size_t)(mtile0    )*KT1*64 + lane)*8;
    const uint16_t* a1p = xfrag + ((size_t)(mtile0 + 1)*KT1*64 + lane)*8;
    const uint16_t* b0p = w1bf + ((size_t)((n0>>4)    )*16*64 + lane)*8;
    const uint16_t* b1p = w1bf + ((size_t)((n0>>4) + 1)*16*64 + lane)*8;
    for (int kk = 0; kk < 16; ++kk) {
        short8 a0 = *reinterpret_cast<const short8*>(a0p + kk*512);
        short8 a1 = *reinterpret_cast<const short8*>(a1p + kk*512);
        short8 b0 = *reinterpret_cast<const short8*>(b0p + kk*512);
        short8 b1 = *reinterpret_cast<const short8*>(b1p + kk*512);
        acc[0][0] = __builtin_amdgcn_mfma_f32_16x16x32_bf16(a0, b0, acc[0][0], 0, 0, 0);
        acc[0][1] = __builtin_amdgcn_mfma_f32_16x16x32_bf16(a0, b1, acc[0][1], 0, 0, 0);
        acc[1][0] = __builtin_amdgcn_mfma_f32_16x16x32_bf16(a1, b0, acc[1][0], 0, 0, 0);
        acc[1][1] = __builtin_amdgcn_mfma_f32_16x16x32_bf16(a1, b1, acc[1][1], 0, 0, 0);
    }
    // bias + gelu -> LDS (local C tile: rows 0..32, cols 0..128)
    #pragma unroll
    for (int nf = 0; nf < 2; ++nf) {
        int coll = wave*32 + nf*16 + l15;
        float bias = b1[blockIdx.y*128 + coll];
        #pragma unroll
        for (int mf = 0; mf < 2; ++mf) {
            #pragma unroll
            for (int r = 0; r < 4; ++r) {
                float v = acc[mf][nf][r] + bias;
                float gl = 0.5f * v * (1.0f + erff(v * 0.7071067811865475f));
                cs[mf*16 + q*4 + r][coll] = f2bf(gl);
            }
        }
    }
    __syncthreads();
    // write out in gemm2-A-frag order: 8 chunks of 1KB, coalesced
    #pragma unroll
    for (int it = 0; it < 2; ++it) {
        int c = (tid >> 6) + 4*it;          // 0..7
        int mt = c >> 2, kk2c = c & 3;
        int l2 = tid & 63;
        int q2 = l2 >> 4, l15_2 = l2 & 15;
        const uint4* src = reinterpret_cast<const uint4*>(&cs[mt*16 + l15_2][kk2c*32 + q2*8]);
        size_t chunk = (size_t)(mtile0 + mt)*KT2 + (blockIdx.y*4 + kk2c);
        uint4* dst = reinterpret_cast<uint4*>(hfrag) + chunk*64 + l2;
        *dst = *src;
    }
}

// K8: y = h @ W2 + b2 + xn -> fp32 (d_out). grid (48, 4) x 256. Tile M=32, N=128.
__global__ __launch_bounds__(256) void k_gemm2(const uint16_t* __restrict__ hfrag,
                                               const uint16_t* __restrict__ w2bf,
                                               const float* __restrict__ b2,
                                               const uint16_t* __restrict__ xrow,
                                               float* __restrict__ y) {
    int tid = threadIdx.x;
    int wave = tid >> 6, lane = tid & 63;
    int q = lane >> 4, l15 = lane & 15;
    int mtile0 = blockIdx.x * 2;
    int m0 = mtile0 * 16;
    int n0 = blockIdx.y * 128 + wave * 32;
    floatx4 acc[2][2] = {};
    const uint16_t* a0p = hfrag + ((size_t)(mtile0    )*KT2*64 + lane)*8;
    const uint16_t* a1p = hfrag + ((size_t)(mtile0 + 1)*KT2*64 + lane)*8;
    const uint16_t* b0p = w2bf + ((size_t)((n0>>4)    )*32*64 + lane)*8;
    const uint16_t* b1p = w2bf + ((size_t)((n0>>4) + 1)*32*64 + lane)*8;
    for (int kk = 0; kk < 32; ++kk) {
        short8 a0 = *reinterpret_cast<const short8*>(a0p + kk*512);
        short8 a1 = *reinterpret_cast<const short8*>(a1p + kk*512);
        short8 b0 = *reinterpret_cast<const short8*>(b0p + kk*512);
        short8 b1 = *reinterpret_cast<const short8*>(b1p + kk*512);
        acc[0][0] = __builtin_amdgcn_mfma_f32_16x16x32_bf16(a0, b0, acc[0][0], 0, 0, 0);
        acc[0][1] = __builtin_amdgcn_mfma_f32_16x16x32_bf16(a0, b1, acc[0][1], 0, 0, 0);
        acc[1][0] = __builtin_amdgcn_mfma_f32_16x16x32_bf16(a1, b0, acc[1][0], 0, 0, 0);
        acc[1][1] = __builtin_amdgcn_mfma_f32_16x16x32_bf16(a1, b1, acc[1][1], 0, 0, 0);
    }
    #pragma unroll
    for (int nf = 0; nf < 2; ++nf) {
        int col = n0 + nf*16 + l15;
        float bias = b2[col];
        #pragma unroll
        for (int mf = 0; mf < 2; ++mf) {
            #pragma unroll
            for (int r = 0; r < 4; ++r) {
                int row = m0 + mf*16 + q*4 + r;
                float xb = bf2f(xrow[(size_t)row*TT + col]);
                y[(size_t)row*TT + col] = acc[mf][nf][r] + bias + xb;
            }
        }
    }
}

// K9: LayerNorm per row over T=512, in-place on d_out. grid 1536 x 64.
__global__ __launch_bounds__(64) void k_ln(float* __restrict__ y,
                                           const float* __restrict__ lng,
                                           const float* __restrict__ lnb) {
    int row = blockIdx.x;
    int lane = threadIdx.x;
    float4* p = reinterpret_cast<float4*>(y + (size_t)row*TT);
    float4 v0 = p[lane*2], v1 = p[lane*2 + 1];
    float s  = v0.x+v0.y+v0.z+v0.w + v1.x+v1.y+v1.z+v1.w;
    float s2 = v0.x*v0.x+v0.y*v0.y+v0.z*v0.z+v0.w*v0.w
             + v1.x*v1.x+v1.y*v1.y+v1.z*v1.z+v1.w*v1.w;
    #pragma unroll
    for (int o = 1; o < 64; o <<= 1) {
        s  += __shfl_xor(s,  o, 64);
        s2 += __shfl_xor(s2, o, 64);
    }
    float mu = s * (1.0f/TT);
    float var = s2 * (1.0f/TT) - mu*mu;
    float rs = rsqrtf(var + 1e-5f);
    const float4* g4 = reinterpret_cast<const float4*>(lng);
    const float4* b4 = reinterpret_cast<const float4*>(lnb);
    float4 g0 = g4[lane*2], g1 = g4[lane*2+1];
    float4 bb0 = b4[lane*2], bb1 = b4[lane*2+1];
    float4 o0, o1;
    o0.x = (v0.x-mu)*rs*g0.x + bb0.x;  o0.y = (v0.y-mu)*rs*g0.y + bb0.y;
    o0.z = (v0.z-mu)*rs*g0.z + bb0.z;  o0.w = (v0.w-mu)*rs*g0.w + bb0.w;
    o1.x = (v1.x-mu)*rs*g1.x + bb1.x;  o1.y = (v1.y-mu)*rs*g1.y + bb1.y;
    o1.z = (v1.z-mu)*rs*g1.z + bb1.z;  o1.w = (v1.w-mu)*rs*g1.w + bb1.w;
    p[lane*2] = o0;  p[lane*2+1] = o1;
}

extern "C" void kernel_launch(void* const* d_in, const int* in_sizes, int n_in,
                              void* d_out, int out_size, void* d_ws, size_t ws_size,
                              hipStream_t stream) {
    (void)in_sizes; (void)n_in; (void)out_size; (void)ws_size;
    const float* residual = (const float*)d_in[0];
    const float* bng = (const float*)d_in[1];
    const float* bnb = (const float*)d_in[2];
    const float* lng = (const float*)d_in[3];
    const float* lnb = (const float*)d_in[4];
    const float* W1  = (const float*)d_in[5];
    const float* b1  = (const float*)d_in[6];
    const float* W2  = (const float*)d_in[7];
    const float* b2  = (const float*)d_in[8];
    float* out = (float*)d_out;
    char* ws = (char*)d_ws;
    float*    x     = (float*)(ws + WSOFF_X);
    uint16_t* hfrag = (uint16_t*)(ws + WSOFF_HFRAG);   // aliases x; x dead by then
    uint16_t* xrow  = (uint16_t*)(ws + WSOFF_XROW);
    uint16_t* xfrag = (uint16_t*)(ws + WSOFF_XFRAG);
    uint16_t* w1bf  = (uint16_t*)(ws + WSOFF_W1BF);
    uint16_t* w2bf  = (uint16_t*)(ws + WSOFF_W2BF);
    float*    A     = (float*)(ws + WSOFF_A);
    float*    s     = (float*)(ws + WSOFF_S);
    float*    bn1   = (float*)(ws + WSOFF_BN1);
    float*    bn2   = (float*)(ws + WSOFF_BN2);
    float*    sc    = (float*)(ws + WSOFF_SC);
    float*    sh    = (float*)(ws + WSOFF_SH);

    (void)hipMemsetAsync(bn1, 0, 2*DD*sizeof(float), stream);
    k_rowsum<<<NROW, 64, 0, stream>>>(residual, s);
    k_softA<<<BB, 128, 0, stream>>>(s, A);
    k_wswiz<<<2048, 64, 0, stream>>>(W1, W2, w1bf, w2bf);
    k_attn3<<<dim3(BB, 8, 4), 256, 0, stream>>>(residual, A, x, bn1, bn2);
    k_bn<<<1, 128, 0, stream>>>(bn1, bn2, bng, bnb, sc, sh);
    k_bnx<<<NROW*TT/1024, 256, 0, stream>>>(x, sc, sh, xrow, xfrag);
    k_gemm1<<<dim3(48, 8), 256, 0, stream>>>(xfrag, w1bf, b1, hfrag);
    k_gemm2<<<dim3(48, 4), 256, 0, stream>>>(hfrag, w2bf, b2, xrow, out);
    k_ln<<<NROW, 64, 0, stream>>>(out, lng, lnb);
}

// Round 6
// 122.797 us; speedup vs baseline: 2.7926x; 1.3906x over previous
//
#include <hip/hip_runtime.h>
#include <math.h>
#include <stdint.h>

#define BB 16
#define DD 96
#define TT 512
#define HH 1024
#define NROW (BB*DD)   // 1536

typedef __attribute__((ext_vector_type(4))) float floatx4;
typedef __attribute__((ext_vector_type(8))) short short8;

// ---------------- ws layout (bytes) ----------------
#define WSOFF_X     0
#define WSOFF_HFRAG 0
#define WSOFF_XROW  (3*1024*1024)                   // xn row-major bf16, 1.5MB
#define WSOFF_XFRAG (WSOFF_XROW + NROW*TT*2)        // xn gemm1-A-frag bf16, 1.5MB
#define WSOFF_W1BF  (WSOFF_XFRAG + NROW*TT*2)       // 1MB
#define WSOFF_W2BF  (WSOFF_W1BF + TT*HH*2)          // 1MB
#define WSOFF_A     (WSOFF_W2BF + HH*TT*2)          // 576KB
#define WSOFF_S     (WSOFF_A + BB*DD*DD*4)
#define WSOFF_SC    (WSOFF_S + NROW*4)
#define WSOFF_SH    (WSOFF_SC + DD*4)

__device__ __forceinline__ uint16_t f2bf(float v) {
    uint32_t u = __float_as_uint(v);
    uint32_t r = 0x7fffu + ((u >> 16) & 1u);
    return (uint16_t)((u + r) >> 16);
}
__device__ __forceinline__ float bf2f(uint16_t v) {
    return __uint_as_float(((uint32_t)v) << 16);
}

#define KT1 (TT/32)    // 16 k-tiles for gemm1 A
#define KT2 (HH/32)    // 32 k-tiles for gemm2 A
__device__ __forceinline__ size_t afrag1_slot(int row, int k) {
    return ((size_t)((row >> 4)*KT1 + (k >> 5))*64 + ((k >> 3) & 3)*16 + (row & 15));
}

// K1: s[row] = sum_t residual[row,t]
__global__ __launch_bounds__(64) void k_rowsum(const float* __restrict__ r,
                                               float* __restrict__ s) {
    int row = blockIdx.x;
    int lane = threadIdx.x;
    const float* p = r + (size_t)row * TT;
    float acc = 0.f;
    #pragma unroll
    for (int i = 0; i < TT/64; ++i) acc += p[lane + i*64];
    #pragma unroll
    for (int o = 32; o > 0; o >>= 1) acc += __shfl_down(acc, o, 64);
    if (lane == 0) s[row] = acc;
}

// K2: A[b][i][j] = softmax_j(s_i*s_j/T^1.5)
__global__ __launch_bounds__(128) void k_softA(const float* __restrict__ s,
                                               float* __restrict__ A) {
    int b = blockIdx.x;
    int i = threadIdx.x;
    __shared__ float sl[DD];
    if (i < DD) sl[i] = s[b*DD + i];
    __syncthreads();
    if (i >= DD) return;
    const float c = 1.0f / (512.0f * 22.627416997969522f);  // T^-1.5
    float si = sl[i] * c;
    float m = -1e30f;
    for (int j = 0; j < DD; ++j) m = fmaxf(m, si * sl[j]);
    float sum = 0.f;
    for (int j = 0; j < DD; ++j) sum += expf(si * sl[j] - m);
    float inv = 1.0f / sum;
    float* Ao = A + ((size_t)b*DD + i)*DD;
    for (int j = 0; j < DD; ++j) Ao[j] = expf(si * sl[j] - m) * inv;
}

// K3: x = A @ r + r.  NO atomics (R5: 24576 atomicAdds onto 12 cache lines = 55us serialization).
__global__ __launch_bounds__(256) void k_attn3(const float* __restrict__ r,
                                               const float* __restrict__ A,
                                               float* __restrict__ x) {
    __shared__ float rlds[DD*64];
    int b = blockIdx.x, chunk = blockIdx.y, ig = blockIdx.z;
    int tid = threadIdx.x;
    int t0 = chunk * 64;
    const float4* rb4 = reinterpret_cast<const float4*>(r + (size_t)b*DD*TT);
    float4* rl4 = reinterpret_cast<float4*>(rlds);
    #pragma unroll
    for (int s = 0; s < 6; ++s) {
        int idx = tid + s*256;
        int i = idx >> 4, t4 = idx & 15;
        rl4[idx] = rb4[(size_t)i*(TT/4) + (t0 >> 2) + t4];
    }
    __syncthreads();

    int wave = __builtin_amdgcn_readfirstlane(tid >> 6);
    int lane = tid & 63;
    int i0 = ig*24 + wave*6;
    const float* Ab = A + ((size_t)b*DD + i0)*DD;

    float acc[6];
    #pragma unroll
    for (int rr = 0; rr < 6; ++rr) acc[rr] = rlds[(i0+rr)*64 + lane];
    #pragma unroll 4
    for (int j4 = 0; j4 < DD/4; ++j4) {
        float4 a[6];
        #pragma unroll
        for (int rr = 0; rr < 6; ++rr)
            a[rr] = *reinterpret_cast<const float4*>(Ab + rr*DD + j4*4);
        float rv[4];
        #pragma unroll
        for (int u = 0; u < 4; ++u) rv[u] = rlds[(j4*4+u)*64 + lane];
        #pragma unroll
        for (int rr = 0; rr < 6; ++rr) {
            acc[rr] = fmaf(a[rr].x, rv[0], acc[rr]);
            acc[rr] = fmaf(a[rr].y, rv[1], acc[rr]);
            acc[rr] = fmaf(a[rr].z, rv[2], acc[rr]);
            acc[rr] = fmaf(a[rr].w, rv[3], acc[rr]);
        }
    }
    #pragma unroll
    for (int rr = 0; rr < 6; ++rr)
        x[((size_t)b*DD + i0 + rr)*TT + t0 + lane] = acc[rr];
}

// K4: per-channel BN stats (deterministic, no atomics) + finalize -> sc/sh.
// grid 96 x 256; block d sums x[b,d,:] over all b.
__global__ __launch_bounds__(256) void k_bnstat(const float* __restrict__ x,
                                                const float* __restrict__ g,
                                                const float* __restrict__ bt,
                                                float* __restrict__ sc,
                                                float* __restrict__ sh) {
    int d = blockIdx.x;
    int tid = threadIdx.x;
    int half = tid >> 7;        // 0..1
    int t4 = tid & 127;         // float4 index in row
    float ls = 0.f, ls2 = 0.f;
    #pragma unroll
    for (int bb = 0; bb < 8; ++bb) {
        int b = bb*2 + half;
        float4 v = *reinterpret_cast<const float4*>(&x[((size_t)b*DD + d)*TT + t4*4]);
        ls  += v.x+v.y+v.z+v.w;
        ls2 += v.x*v.x+v.y*v.y+v.z*v.z+v.w*v.w;
    }
    #pragma unroll
    for (int o = 32; o > 0; o >>= 1) {
        ls  += __shfl_down(ls,  o, 64);
        ls2 += __shfl_down(ls2, o, 64);
    }
    __shared__ float r1[4], r2[4];
    int wid = tid >> 6;
    if ((tid & 63) == 0) { r1[wid] = ls; r2[wid] = ls2; }
    __syncthreads();
    if (tid == 0) {
        float s1 = r1[0]+r1[1]+r1[2]+r1[3];
        float s2 = r2[0]+r2[1]+r2[2]+r2[3];
        const float invn = 1.0f / (float)(BB*TT);
        float mu  = s1 * invn;
        float var = s2 * invn - mu*mu;
        float rs  = rsqrtf(var + 1e-5f);
        float scale = rs * g[d];
        sc[d] = scale;
        sh[d] = bt[d] - mu * scale;
    }
}

// K5: xn = BN(x) -> bf16, row-major + gemm1-A-frag order.
__global__ __launch_bounds__(256) void k_bnx(const float* __restrict__ x,
                                             const float* __restrict__ sc,
                                             const float* __restrict__ sh,
                                             uint16_t* __restrict__ xrow,
                                             uint16_t* __restrict__ xfrag) {
    int g = blockIdx.x*256 + threadIdx.x;
    int row = g >> 7;
    int k0 = (g & 127) * 4;
    int d = row % DD;
    float4 v = *reinterpret_cast<const float4*>(&x[(size_t)row*TT + k0]);
    float scd = sc[d], shd = sh[d];
    ushort4 o;
    o.x = f2bf(v.x*scd + shd);
    o.y = f2bf(v.y*scd + shd);
    o.z = f2bf(v.z*scd + shd);
    o.w = f2bf(v.w*scd + shd);
    *reinterpret_cast<ushort4*>(&xrow[(size_t)row*TT + k0]) = o;
    size_t slot = afrag1_slot(row, k0);
    *reinterpret_cast<ushort4*>(&xfrag[slot*8 + (k0 & 7)]) = o;
}

// K6: swizzle W1/W2 fp32 -> bf16 B-fragment layout.
__global__ __launch_bounds__(64) void k_wswiz(const float* __restrict__ W1,
                                              const float* __restrict__ W2,
                                              uint16_t* __restrict__ w1bf,
                                              uint16_t* __restrict__ w2bf) {
    int blk = blockIdx.x;
    int lane = threadIdx.x;
    int q = lane >> 4, l15 = lane & 15;
    const float* W; uint16_t* out; int KT, N, b;
    if (blk < 1024) { W = W1; out = w1bf; KT = 16; N = 1024; b = blk; }
    else            { W = W2; out = w2bf; KT = 32; N = 512;  b = blk - 1024; }
    int tile_n = b / KT, tile_k = b % KT;
    const float* src = W + (size_t)(tile_k*32 + q*8)*N + tile_n*16 + l15;
    uint16_t tmp[8];
    #pragma unroll
    for (int j = 0; j < 8; ++j) tmp[j] = f2bf(src[(size_t)j*N]);
    uint16_t* dst = out + ((size_t)b*64 + lane)*8;
    *reinterpret_cast<ushort4*>(dst)     = *reinterpret_cast<ushort4*>(&tmp[0]);
    *reinterpret_cast<ushort4*>(dst + 4) = *reinterpret_cast<ushort4*>(&tmp[4]);
}

// K7: h = gelu(xn @ W1 + b1) in gemm2-A-frag order. grid (96, 8) x 256. M=16, N=128.
__global__ __launch_bounds__(256) void k_gemm1(const uint16_t* __restrict__ xfrag,
                                               const uint16_t* __restrict__ w1bf,
                                               const float* __restrict__ b1,
                                               uint16_t* __restrict__ hfrag) {
    __shared__ __align__(16) uint16_t cs[16][136];
    int tid = threadIdx.x;
    int wave = tid >> 6, lane = tid & 63;
    int q = lane >> 4, l15 = lane & 15;
    int mtile = blockIdx.x;
    int n0 = blockIdx.y * 128 + wave * 32;
    floatx4 acc[2] = {};
    const uint16_t* ap  = xfrag + ((size_t)mtile*KT1*64 + lane)*8;
    const uint16_t* b0p = w1bf + ((size_t)((n0>>4)    )*16*64 + lane)*8;
    const uint16_t* b1p = w1bf + ((size_t)((n0>>4) + 1)*16*64 + lane)*8;
    #pragma unroll
    for (int kk = 0; kk < 16; ++kk) {
        short8 a  = *reinterpret_cast<const short8*>(ap  + kk*512);
        short8 b0 = *reinterpret_cast<const short8*>(b0p + kk*512);
        short8 b1 = *reinterpret_cast<const short8*>(b1p + kk*512);
        acc[0] = __builtin_amdgcn_mfma_f32_16x16x32_bf16(a, b0, acc[0], 0, 0, 0);
        acc[1] = __builtin_amdgcn_mfma_f32_16x16x32_bf16(a, b1, acc[1], 0, 0, 0);
    }
    #pragma unroll
    for (int nf = 0; nf < 2; ++nf) {
        int coll = wave*32 + nf*16 + l15;
        float bias = b1[blockIdx.y*128 + coll];
        #pragma unroll
        for (int r = 0; r < 4; ++r) {
            float v = acc[nf][r] + bias;
            float gl = 0.5f * v * (1.0f + erff(v * 0.7071067811865475f));
            cs[q*4 + r][coll] = f2bf(gl);
        }
    }
    __syncthreads();
    // wave w writes k-chunk c=w of this block's 128-col slice, gemm2-A-frag order
    int c = wave;
    const uint4* src = reinterpret_cast<const uint4*>(&cs[l15][c*32 + q*8]);
    size_t chunk = (size_t)mtile*KT2 + (blockIdx.y*4 + c);
    reinterpret_cast<uint4*>(hfrag)[chunk*64 + lane] = *src;
}

// K8: y = h @ W2 + b2 + xn -> fp32. grid (96, 4) x 256. M=16, N=128.
__global__ __launch_bounds__(256) void k_gemm2(const uint16_t* __restrict__ hfrag,
                                               const uint16_t* __restrict__ w2bf,
                                               const float* __restrict__ b2,
                                               const uint16_t* __restrict__ xrow,
                                               float* __restrict__ y) {
    int tid = threadIdx.x;
    int wave = tid >> 6, lane = tid & 63;
    int q = lane >> 4, l15 = lane & 15;
    int mtile = blockIdx.x;
    int m0 = mtile * 16;
    int n0 = blockIdx.y * 128 + wave * 32;
    floatx4 acc[2] = {};
    const uint16_t* ap  = hfrag + ((size_t)mtile*KT2*64 + lane)*8;
    const uint16_t* b0p = w2bf + ((size_t)((n0>>4)    )*32*64 + lane)*8;
    const uint16_t* b1p = w2bf + ((size_t)((n0>>4) + 1)*32*64 + lane)*8;
    #pragma unroll
    for (int kk = 0; kk < 32; ++kk) {
        short8 a  = *reinterpret_cast<const short8*>(ap  + kk*512);
        short8 b0 = *reinterpret_cast<const short8*>(b0p + kk*512);
        short8 b1 = *reinterpret_cast<const short8*>(b1p + kk*512);
        acc[0] = __builtin_amdgcn_mfma_f32_16x16x32_bf16(a, b0, acc[0], 0, 0, 0);
        acc[1] = __builtin_amdgcn_mfma_f32_16x16x32_bf16(a, b1, acc[1], 0, 0, 0);
    }
    #pragma unroll
    for (int nf = 0; nf < 2; ++nf) {
        int col = n0 + nf*16 + l15;
        float bias = b2[col];
        #pragma unroll
        for (int r = 0; r < 4; ++r) {
            int row = m0 + q*4 + r;
            float xb = bf2f(xrow[(size_t)row*TT + col]);
            y[(size_t)row*TT + col] = acc[nf][r] + bias + xb;
        }
    }
}

// K9: LayerNorm per row over T=512, in-place on d_out.
__global__ __launch_bounds__(64) void k_ln(float* __restrict__ y,
                                           const float* __restrict__ lng,
                                           const float* __restrict__ lnb) {
    int row = blockIdx.x;
    int lane = threadIdx.x;
    float4* p = reinterpret_cast<float4*>(y + (size_t)row*TT);
    float4 v0 = p[lane*2], v1 = p[lane*2 + 1];
    float s  = v0.x+v0.y+v0.z+v0.w + v1.x+v1.y+v1.z+v1.w;
    float s2 = v0.x*v0.x+v0.y*v0.y+v0.z*v0.z+v0.w*v0.w
             + v1.x*v1.x+v1.y*v1.y+v1.z*v1.z+v1.w*v1.w;
    #pragma unroll
    for (int o = 1; o < 64; o <<= 1) {
        s  += __shfl_xor(s,  o, 64);
        s2 += __shfl_xor(s2, o, 64);
    }
    float mu = s * (1.0f/TT);
    float var = s2 * (1.0f/TT) - mu*mu;
    float rs = rsqrtf(var + 1e-5f);
    const float4* g4 = reinterpret_cast<const float4*>(lng);
    const float4* b4 = reinterpret_cast<const float4*>(lnb);
    float4 g0 = g4[lane*2], g1 = g4[lane*2+1];
    float4 bb0 = b4[lane*2], bb1 = b4[lane*2+1];
    float4 o0, o1;
    o0.x = (v0.x-mu)*rs*g0.x + bb0.x;  o0.y = (v0.y-mu)*rs*g0.y + bb0.y;
    o0.z = (v0.z-mu)*rs*g0.z + bb0.z;  o0.w = (v0.w-mu)*rs*g0.w + bb0.w;
    o1.x = (v1.x-mu)*rs*g1.x + bb1.x;  o1.y = (v1.y-mu)*rs*g1.y + bb1.y;
    o1.z = (v1.z-mu)*rs*g1.z + bb1.z;  o1.w = (v1.w-mu)*rs*g1.w + bb1.w;
    p[lane*2] = o0;  p[lane*2+1] = o1;
}

extern "C" void kernel_launch(void* const* d_in, const int* in_sizes, int n_in,
                              void* d_out, int out_size, void* d_ws, size_t ws_size,
                              hipStream_t stream) {
    (void)in_sizes; (void)n_in; (void)out_size; (void)ws_size;
    const float* residual = (const float*)d_in[0];
    const float* bng = (const float*)d_in[1];
    const float* bnb = (const float*)d_in[2];
    const float* lng = (const float*)d_in[3];
    const float* lnb = (const float*)d_in[4];
    const float* W1  = (const float*)d_in[5];
    const float* b1  = (const float*)d_in[6];
    const float* W2  = (const float*)d_in[7];
    const float* b2  = (const float*)d_in[8];
    float* out = (float*)d_out;
    char* ws = (char*)d_ws;
    float*    x     = (float*)(ws + WSOFF_X);
    uint16_t* hfrag = (uint16_t*)(ws + WSOFF_HFRAG);   // aliases x; x dead by then
    uint16_t* xrow  = (uint16_t*)(ws + WSOFF_XROW);
    uint16_t* xfrag = (uint16_t*)(ws + WSOFF_XFRAG);
    uint16_t* w1bf  = (uint16_t*)(ws + WSOFF_W1BF);
    uint16_t* w2bf  = (uint16_t*)(ws + WSOFF_W2BF);
    float*    A     = (float*)(ws + WSOFF_A);
    float*    s     = (float*)(ws + WSOFF_S);
    float*    sc    = (float*)(ws + WSOFF_SC);
    float*    sh    = (float*)(ws + WSOFF_SH);

    k_rowsum<<<NROW, 64, 0, stream>>>(residual, s);
    k_softA<<<BB, 128, 0, stream>>>(s, A);
    k_wswiz<<<2048, 64, 0, stream>>>(W1, W2, w1bf, w2bf);
    k_attn3<<<dim3(BB, 8, 4), 256, 0, stream>>>(residual, A, x);
    k_bnstat<<<DD, 256, 0, stream>>>(x, bng, bnb, sc, sh);
    k_bnx<<<NROW*TT/1024, 256, 0, stream>>>(x, sc, sh, xrow, xfrag);
    k_gemm1<<<dim3(96, 8), 256, 0, stream>>>(xfrag, w1bf, b1, hfrag);
    k_gemm2<<<dim3(96, 4), 256, 0, stream>>>(hfrag, w2bf, b2, xrow, out);
    k_ln<<<NROW, 64, 0, stream>>>(out, lng, lnb);
}